// Round 1
// baseline (1092.085 us; speedup 1.0000x reference)
//
#include <hip/hip_runtime.h>
#include <math.h>

#define B_   32
#define L_   2048
#define DSEQ 1024
#define DGLB 1024
#define H_   16
#define DK_  64
#define DV_  64
#define LT   64
#define NT   (L_/LT)      // 32
#define PSTRIDE 66        // m, s, y[64]

using u16    = unsigned short;
using bf16x8 = __attribute__((ext_vector_type(8))) short;
using f32x4  = __attribute__((ext_vector_type(4))) float;

__device__ __forceinline__ u16 f2bf(float x) {
  union { float f; unsigned int u; } v; v.f = x;
  return (u16)((v.u + 0x7fffu + ((v.u >> 16) & 1u)) >> 16);   // RNE
}

// Wc[h][j][d] (bf16, k-contiguous): j<64 -> Wk[h,:,j], else Wv[h,:,j-64]
__global__ void pack_w_kernel(const float* __restrict__ Wk,
                              const float* __restrict__ Wv,
                              u16* __restrict__ Wc) {
  const int h = blockIdx.x, j = blockIdx.y;
  const float* src = (j < DK_) ? (Wk + (size_t)h*DSEQ*DK_ + j)
                               : (Wv + (size_t)h*DSEQ*DV_ + (j - DK_));
  u16* dst = Wc + ((size_t)h*128 + j)*DSEQ;
  for (int d = threadIdx.x; d < DSEQ; d += blockDim.x)
    dst[d] = f2bf(src[(size_t)d*64]);
}

// Q[b][h][k] = tanh(sum_d X[b,d]*Wq[h,d,k]); grid (H, B/4), block 64
__global__ void q_proj_kernel(const float* __restrict__ X,
                              const float* __restrict__ Wq,
                              float* __restrict__ Q) {
  const int h = blockIdx.x, b0 = blockIdx.y*4, k = threadIdx.x;
  const float* w = Wq + (size_t)h*DGLB*DK_ + k;
  float a0=0.f, a1=0.f, a2=0.f, a3=0.f;
  for (int d = 0; d < DGLB; ++d) {
    float wv = w[(size_t)d*DK_];
    a0 += X[(size_t)(b0+0)*DGLB + d]*wv;
    a1 += X[(size_t)(b0+1)*DGLB + d]*wv;
    a2 += X[(size_t)(b0+2)*DGLB + d]*wv;
    a3 += X[(size_t)(b0+3)*DGLB + d]*wv;
  }
  Q[((size_t)(b0+0)*H_+h)*DK_+k] = tanhf(a0);
  Q[((size_t)(b0+1)*H_+h)*DK_+k] = tanhf(a1);
  Q[((size_t)(b0+2)*H_+h)*DK_+k] = tanhf(a2);
  Q[((size_t)(b0+3)*H_+h)*DK_+k] = tanhf(a3);
}

// grid (NT, B), block 256 (4 waves). Wave w owns cols [32w,32w+32) of the
// 128-wide per-head output (cols 0..63 = K-proj, 64..127 = V-proj).
__global__ __launch_bounds__(256) void fused_kernel(
    const float* __restrict__ S, const u16* __restrict__ Wc,
    const float* __restrict__ Q, float* __restrict__ part) {
  __shared__ u16  Slds[LT*DSEQ];      // 128 KB, XOR-swizzled rows
  __shared__ float lpart[2][LT];      // logit partials from waves 0,1

  const int t = blockIdx.x, b = blockIdx.y;
  const int tid  = threadIdx.x;
  const int wave = tid >> 6, lane = tid & 63;
  const int lhi  = lane >> 4, llo = lane & 15;

  { // ---- stage S tile: fp32 -> bf16, swizzled ----
    const float4* Sv = (const float4*)(S + ((size_t)b*L_ + (size_t)t*LT)*DSEQ);
    for (int it = 0; it < 64; ++it) {
      int f    = it*256 + tid;
      int row  = f >> 8;            // 256 float4 per row
      int colb = (f & 255)*8;       // byte col (4 bf16 = 8B)
      float4 v = Sv[f];
      ushort4 wv;
      wv.x = f2bf(v.x); wv.y = f2bf(v.y); wv.z = f2bf(v.z); wv.w = f2bf(v.w);
      *(ushort4*)((char*)Slds + (row*2048 + (colb ^ ((row & 7) << 4)))) = wv;
    }
  }
  __syncthreads();

  const int wcol = wave*32;
  const int sw   = (llo & 7) << 4;
  int arow[4];
  #pragma unroll
  for (int rt = 0; rt < 4; ++rt) arow[rt] = (rt*16 + llo)*2048;

  for (int h = 0; h < H_; ++h) {
    const u16* wp0 = Wc + (size_t)h*128*DSEQ + (size_t)(wcol + llo)*DSEQ + lhi*8;
    const u16* wp1 = wp0 + 16*DSEQ;
    f32x4 acc[4][2];
    #pragma unroll
    for (int rt = 0; rt < 4; ++rt) {
      acc[rt][0] = {0.f,0.f,0.f,0.f};
      acc[rt][1] = {0.f,0.f,0.f,0.f};
    }

    #pragma unroll 4
    for (int k0 = 0; k0 < DSEQ; k0 += 32) {
      bf16x8 bf0 = *(const bf16x8*)(wp0 + k0);
      bf16x8 bf1 = *(const bf16x8*)(wp1 + k0);
      const int colb = (k0*2 + lhi*16) ^ sw;
      #pragma unroll
      for (int rt = 0; rt < 4; ++rt) {
        bf16x8 af = *(const bf16x8*)((const char*)Slds + (arow[rt] + colb));
        acc[rt][0] = __builtin_amdgcn_mfma_f32_16x16x32_bf16(af, bf0, acc[rt][0], 0,0,0);
        acc[rt][1] = __builtin_amdgcn_mfma_f32_16x16x32_bf16(af, bf1, acc[rt][1], 0,0,0);
      }
    }

    if (wave < 2) {
      // K-proj: tanh, dot with Q, reduce over 16 k's (lane&15 groups)
      const float* Qb = Q + ((size_t)b*H_ + h)*DK_;
      float q0 = Qb[wcol + llo];
      float q1 = Qb[wcol + 16 + llo];
      #pragma unroll
      for (int rt = 0; rt < 4; ++rt) {
        #pragma unroll
        for (int r = 0; r < 4; ++r) {
          float p = q0*tanhf(acc[rt][0][r]) + q1*tanhf(acc[rt][1][r]);
          p += __shfl_xor(p, 1); p += __shfl_xor(p, 2);
          p += __shfl_xor(p, 4); p += __shfl_xor(p, 8);
          if (llo == 0) lpart[wave][rt*16 + lhi*4 + r] = p;
        }
      }
    } else {
      // V-proj: exact gelu in place
      #pragma unroll
      for (int rt = 0; rt < 4; ++rt)
        #pragma unroll
        for (int ct = 0; ct < 2; ++ct)
          #pragma unroll
          for (int r = 0; r < 4; ++r) {
            float x = acc[rt][ct][r];
            acc[rt][ct][r] = 0.5f*x*(1.f + erff(x*0.70710678118654752f));
          }
    }
    __syncthreads();

    // all waves: per-tile softmax stats (lane <-> row l, LT==64)
    float lg = (lpart[0][lane] + lpart[1][lane]) * 0.125f;  // 1/sqrt(64)
    float mx = lg;
    #pragma unroll
    for (int mk = 1; mk < 64; mk <<= 1) mx = fmaxf(mx, __shfl_xor(mx, mk));
    float ev = __expf(lg - mx);
    float sv = ev;
    #pragma unroll
    for (int mk = 1; mk < 64; mk <<= 1) sv += __shfl_xor(sv, mk);

    if (wave >= 2) {
      float yp0 = 0.f, yp1 = 0.f;
      #pragma unroll
      for (int rt = 0; rt < 4; ++rt) {
        #pragma unroll
        for (int r = 0; r < 4; ++r) {
          float el = __shfl(ev, rt*16 + lhi*4 + r);   // e for this acc row
          yp0 += el*acc[rt][0][r];
          yp1 += el*acc[rt][1][r];
        }
      }
      yp0 += __shfl_xor(yp0, 16); yp0 += __shfl_xor(yp0, 32);
      yp1 += __shfl_xor(yp1, 16); yp1 += __shfl_xor(yp1, 32);
      float* pt = part + (((size_t)b*H_ + h)*NT + t)*PSTRIDE;
      if (lhi == 0) {
        pt[2 + (wave-2)*32 + llo]      = yp0;
        pt[2 + (wave-2)*32 + 16 + llo] = yp1;
      }
      if (tid == 128) { pt[0] = mx; pt[1] = sv; }
    }
    __syncthreads();
  }
}

// merge NT tile-partials per (b,h); grid (H, B), block 64 (v = thread)
__global__ void finalize_kernel(const float* __restrict__ part,
                                float* __restrict__ out) {
  const int h = blockIdx.x, b = blockIdx.y, v = threadIdx.x;
  const float* p = part + ((size_t)b*H_ + h)*(size_t)NT*PSTRIDE;
  float M = -3.0e38f;
  for (int tt = 0; tt < NT; ++tt) M = fmaxf(M, p[tt*PSTRIDE]);
  float ss = 0.f, y = 0.f;
  for (int tt = 0; tt < NT; ++tt) {
    float w = expf(p[tt*PSTRIDE] - M);
    ss += w*p[tt*PSTRIDE + 1];
    y  += w*p[tt*PSTRIDE + 2 + v];
  }
  out[((size_t)b*H_ + h)*DV_ + v] = y/ss;
}

extern "C" void kernel_launch(void* const* d_in, const int* in_sizes, int n_in,
                              void* d_out, int out_size, void* d_ws, size_t ws_size,
                              hipStream_t stream) {
  const float* X  = (const float*)d_in[0];
  const float* S  = (const float*)d_in[1];
  const float* Wq = (const float*)d_in[2];
  const float* Wk = (const float*)d_in[3];
  const float* Wv = (const float*)d_in[4];
  float* out = (float*)d_out;

  char* ws = (char*)d_ws;
  u16*   Wc   = (u16*)ws;                              // 16*128*1024*2 = 4 MiB
  float* Qbuf = (float*)(ws + (4u<<20));               // 128 KiB
  float* part = (float*)(ws + (4u<<20) + (128u<<10));  // 32*16*32*66*4 ≈ 4.3 MiB

  pack_w_kernel  <<<dim3(H_, 128),  256, 0, stream>>>(Wk, Wv, Wc);
  q_proj_kernel  <<<dim3(H_, B_/4),  64, 0, stream>>>(X, Wq, Qbuf);
  fused_kernel   <<<dim3(NT, B_),   256, 0, stream>>>(S, Wc, Qbuf, part);
  finalize_kernel<<<dim3(H_, B_),    64, 0, stream>>>(part, out);
}

// Round 2
// 701.906 us; speedup vs baseline: 1.5559x; 1.5559x over previous
//
#include <hip/hip_runtime.h>
#include <math.h>

#define B_   32
#define L_   2048
#define DSEQ 1024
#define DGLB 1024
#define H_   16
#define DK_  64
#define DV_  64
#define LT   64
#define NT   (L_/LT)      // 32
#define PSTRIDE 66        // m, s, y[64]

using u16    = unsigned short;
using bf16x8 = __attribute__((ext_vector_type(8))) short;
using f32x4  = __attribute__((ext_vector_type(4))) float;

__device__ __forceinline__ u16 f2bf(float x) {
  union { float f; unsigned int u; } v; v.f = x;
  return (u16)((v.u + 0x7fffu + ((v.u >> 16) & 1u)) >> 16);   // RNE
}

// Wc[h][j][d] (bf16, k-contiguous): j<64 -> Wk[h,:,j], else Wv[h,:,j-64]
__global__ void pack_w_kernel(const float* __restrict__ Wk,
                              const float* __restrict__ Wv,
                              u16* __restrict__ Wc) {
  const int h = blockIdx.x, j = blockIdx.y;
  const float* src = (j < DK_) ? (Wk + (size_t)h*DSEQ*DK_ + j)
                               : (Wv + (size_t)h*DSEQ*DV_ + (j - DK_));
  u16* dst = Wc + ((size_t)h*128 + j)*DSEQ;
  for (int d = threadIdx.x; d < DSEQ; d += blockDim.x)
    dst[d] = f2bf(src[(size_t)d*64]);
}

// Q[b][h][k] = tanh(sum_d X[b,d]*Wq[h,d,k]); grid (H, B/4), block 64
__global__ void q_proj_kernel(const float* __restrict__ X,
                              const float* __restrict__ Wq,
                              float* __restrict__ Q) {
  const int h = blockIdx.x, b0 = blockIdx.y*4, k = threadIdx.x;
  const float* w = Wq + (size_t)h*DGLB*DK_ + k;
  float a0=0.f, a1=0.f, a2=0.f, a3=0.f;
  for (int d = 0; d < DGLB; ++d) {
    float wv = w[(size_t)d*DK_];
    a0 += X[(size_t)(b0+0)*DGLB + d]*wv;
    a1 += X[(size_t)(b0+1)*DGLB + d]*wv;
    a2 += X[(size_t)(b0+2)*DGLB + d]*wv;
    a3 += X[(size_t)(b0+3)*DGLB + d]*wv;
  }
  Q[((size_t)(b0+0)*H_+h)*DK_+k] = tanhf(a0);
  Q[((size_t)(b0+1)*H_+h)*DK_+k] = tanhf(a1);
  Q[((size_t)(b0+2)*H_+h)*DK_+k] = tanhf(a2);
  Q[((size_t)(b0+3)*H_+h)*DK_+k] = tanhf(a3);
}

// grid (NT, B), 512 threads = 8 waves, 2 waves/SIMD.
// Pass p (0..3) processes heads 4p..4p+3. Wave w: head 4p + (w>>1);
// even wave -> K-proj cols 0..63, odd wave -> V-proj cols 0..63.
// Each wave: 64 rows x 64 cols, nB=4 (16 MFMA per K=32 step).
__global__ __launch_bounds__(512, 2) void fused_kernel(
    const float* __restrict__ S, const u16* __restrict__ Wc,
    const float* __restrict__ Q, float* __restrict__ part) {
  __shared__ u16   Slds[LT*DSEQ];        // 128 KB, XOR-swizzled rows
  __shared__ float lpart[2][4][64];      // logits, double-buffered by pass

  const int t = blockIdx.x, b = blockIdx.y;
  const int tid  = threadIdx.x;
  const int wave = tid >> 6, lane = tid & 63;
  const int lhi  = lane >> 4, llo = lane & 15;
  const int isV  = wave & 1, hp = wave >> 1;

  { // ---- stage S tile: fp32 -> bf16, swizzled (row&15)<<4 ----
    const float4* Sv = (const float4*)(S + ((size_t)b*L_ + (size_t)t*LT)*DSEQ);
    #pragma unroll
    for (int it = 0; it < 32; ++it) {
      int f    = it*512 + tid;
      int row  = f >> 8;            // 256 float4 per row
      int cb   = (f & 255)*8;       // byte col
      float4 v = Sv[f];
      ushort4 wv;
      wv.x = f2bf(v.x); wv.y = f2bf(v.y); wv.z = f2bf(v.z); wv.w = f2bf(v.w);
      *(ushort4*)((char*)Slds + (row*2048 + (cb ^ ((row & 15) << 4)))) = wv;
    }
  }
  __syncthreads();

  int arow[4];
  #pragma unroll
  for (int rt = 0; rt < 4; ++rt) arow[rt] = (rt*16 + llo)*2048;
  const int swz = llo << 4;

  for (int p = 0; p < 4; ++p) {
    const int h = p*4 + hp;
    const u16* wp = Wc + ((size_t)(h*128 + isV*64 + llo))*DSEQ + lhi*8;

    f32x4 acc[4][4];
    #pragma unroll
    for (int rt = 0; rt < 4; ++rt)
      #pragma unroll
      for (int c = 0; c < 4; ++c) acc[rt][c] = {0.f,0.f,0.f,0.f};

    bf16x8 bnx[4];
    #pragma unroll
    for (int c = 0; c < 4; ++c) bnx[c] = *(const bf16x8*)(wp + c*16*DSEQ);

    #pragma unroll 2
    for (int k0 = 0; k0 < DSEQ; k0 += 32) {
      bf16x8 bc[4];
      #pragma unroll
      for (int c = 0; c < 4; ++c) bc[c] = bnx[c];
      const int kn = (k0 + 32) & (DSEQ - 1);   // wraps to 0 on last iter
      #pragma unroll
      for (int c = 0; c < 4; ++c) bnx[c] = *(const bf16x8*)(wp + c*16*DSEQ + kn);

      const int colb = (k0*2 + lhi*16) ^ swz;
      #pragma unroll
      for (int rt = 0; rt < 4; ++rt) {
        bf16x8 af = *(const bf16x8*)((const char*)Slds + (arow[rt] + colb));
        #pragma unroll
        for (int c = 0; c < 4; ++c)
          acc[rt][c] = __builtin_amdgcn_mfma_f32_16x16x32_bf16(af, bc[c], acc[rt][c], 0,0,0);
      }
    }

    if (!isV) {
      // K-proj: tanh, dot with Q over 64 k-cols, reduce -> logit per row
      const float* Qb = Q + ((size_t)b*H_ + h)*DK_;
      float q[4];
      #pragma unroll
      for (int c = 0; c < 4; ++c) q[c] = Qb[16*c + llo];
      #pragma unroll
      for (int rt = 0; rt < 4; ++rt) {
        #pragma unroll
        for (int r = 0; r < 4; ++r) {
          float pl = 0.f;
          #pragma unroll
          for (int c = 0; c < 4; ++c) pl += q[c]*tanhf(acc[rt][c][r]);
          pl += __shfl_xor(pl, 1); pl += __shfl_xor(pl, 2);
          pl += __shfl_xor(pl, 4); pl += __shfl_xor(pl, 8);
          if (llo == 0) lpart[p & 1][hp][rt*16 + lhi*4 + r] = pl;
        }
      }
    } else {
      // V-proj: exact gelu in place
      #pragma unroll
      for (int rt = 0; rt < 4; ++rt)
        #pragma unroll
        for (int c = 0; c < 4; ++c)
          #pragma unroll
          for (int r = 0; r < 4; ++r) {
            float x = acc[rt][c][r];
            acc[rt][c][r] = 0.5f*x*(1.f + erff(x*0.70710678118654752f));
          }
    }
    __syncthreads();

    if (isV) {
      // softmax stats over this tile's 64 rows (lane <-> row)
      float lg = lpart[p & 1][hp][lane] * 0.125f;   // 1/sqrt(64)
      float mx = lg;
      #pragma unroll
      for (int mk = 1; mk < 64; mk <<= 1) mx = fmaxf(mx, __shfl_xor(mx, mk));
      float ev = __expf(lg - mx);
      float sv = ev;
      #pragma unroll
      for (int mk = 1; mk < 64; mk <<= 1) sv += __shfl_xor(sv, mk);

      // e for the 16 rows this lane's acc covers
      float er[16];
      #pragma unroll
      for (int rt = 0; rt < 4; ++rt)
        #pragma unroll
        for (int r = 0; r < 4; ++r)
          er[rt*4 + r] = __shfl(ev, rt*16 + lhi*4 + r);

      float* pt = part + (((size_t)b*H_ + h)*NT + t)*PSTRIDE;
      #pragma unroll
      for (int c = 0; c < 4; ++c) {
        float y = 0.f;
        #pragma unroll
        for (int rt = 0; rt < 4; ++rt)
          #pragma unroll
          for (int r = 0; r < 4; ++r)
            y += er[rt*4 + r]*acc[rt][c][r];
        y += __shfl_xor(y, 16); y += __shfl_xor(y, 32);
        if (lhi == 0) pt[2 + 16*c + llo] = y;
      }
      if (lane == 0) { pt[0] = mx; pt[1] = sv; }
    }
  }
}

// merge NT tile-partials per (b,h); grid (H, B), block 64 (v = thread)
__global__ void finalize_kernel(const float* __restrict__ part,
                                float* __restrict__ out) {
  const int h = blockIdx.x, b = blockIdx.y, v = threadIdx.x;
  const float* p = part + ((size_t)b*H_ + h)*(size_t)NT*PSTRIDE;
  float M = -3.0e38f;
  for (int tt = 0; tt < NT; ++tt) M = fmaxf(M, p[tt*PSTRIDE]);
  float ss = 0.f, y = 0.f;
  for (int tt = 0; tt < NT; ++tt) {
    float w = expf(p[tt*PSTRIDE] - M);
    ss += w*p[tt*PSTRIDE + 1];
    y  += w*p[tt*PSTRIDE + 2 + v];
  }
  out[((size_t)b*H_ + h)*DV_ + v] = y/ss;
}

extern "C" void kernel_launch(void* const* d_in, const int* in_sizes, int n_in,
                              void* d_out, int out_size, void* d_ws, size_t ws_size,
                              hipStream_t stream) {
  const float* X  = (const float*)d_in[0];
  const float* S  = (const float*)d_in[1];
  const float* Wq = (const float*)d_in[2];
  const float* Wk = (const float*)d_in[3];
  const float* Wv = (const float*)d_in[4];
  float* out = (float*)d_out;

  char* ws = (char*)d_ws;
  u16*   Wc   = (u16*)ws;                              // 16*128*1024*2 = 4 MiB
  float* Qbuf = (float*)(ws + (4u<<20));               // 128 KiB
  float* part = (float*)(ws + (4u<<20) + (128u<<10));  // ~4.3 MiB

  pack_w_kernel  <<<dim3(H_, 128),  256, 0, stream>>>(Wk, Wv, Wc);
  q_proj_kernel  <<<dim3(H_, B_/4),  64, 0, stream>>>(X, Wq, Qbuf);
  fused_kernel   <<<dim3(NT, B_),   512, 0, stream>>>(S, Wc, Qbuf, part);
  finalize_kernel<<<dim3(H_, B_),    64, 0, stream>>>(part, out);
}